// Round 2
// baseline (2972.598 us; speedup 1.0000x reference)
//
#include <hip/hip_runtime.h>

#define N_NODES 100000
#define N_EDGES 1600000
#define FDIM 128
#define OUTF 16
#define NGRAPH 256

// ---------------- degree / norm ----------------
__global__ void k_deg_init(float* __restrict__ deg) {
    int i = blockIdx.x * 256 + threadIdx.x;
    if (i < N_NODES) deg[i] = 1.0f;   // self-loop contributes 1
}

__global__ void k_deg_edges(const int* __restrict__ dst, float* __restrict__ deg) {
    int e = blockIdx.x * 256 + threadIdx.x;
    if (e < N_EDGES) atomicAdd(&deg[dst[e]], 1.0f);
}

__global__ void k_dinv(float* __restrict__ deg) {
    int i = blockIdx.x * 256 + threadIdx.x;
    if (i < N_NODES) deg[i] = rsqrtf(deg[i]);   // deg >= 1 always
}

// ---------------- h = x @ W1 (fp32, LDS tiled, 4x4 register block) ----------------
#define GR 32   // rows per block
__launch_bounds__(256)
__global__ void k_gemm(const float* __restrict__ x, const float* __restrict__ W,
                       float* __restrict__ h) {
    __shared__ float Wl[128 * 128];   // 64 KB, layout W[k][c]
    __shared__ float Xl[GR][128];     // 16 KB
    int t = threadIdx.x;

    const float4* W4 = (const float4*)W;
    float4* Wl4 = (float4*)Wl;
#pragma unroll
    for (int i = 0; i < 16; ++i) Wl4[t + i * 256] = W4[t + i * 256];

    int r0 = blockIdx.x * GR;
    const float4* X4 = (const float4*)(x + (long)r0 * FDIM);
    float4* Xl4 = (float4*)&Xl[0][0];
#pragma unroll
    for (int i = 0; i < 4; ++i) Xl4[t + i * 256] = X4[t + i * 256];
    __syncthreads();

    int cg = t & 31;   // columns 4*cg .. 4*cg+3
    int rg = t >> 5;   // rows rg*4 .. rg*4+3
    float acc[4][4] = {};
    for (int k = 0; k < 128; k += 4) {
        float4 xv[4];
#pragma unroll
        for (int r = 0; r < 4; ++r) xv[r] = *(const float4*)&Xl[rg * 4 + r][k];
#pragma unroll
        for (int kk = 0; kk < 4; ++kk) {
            float4 wv = *(const float4*)&Wl[(k + kk) * 128 + cg * 4];
#pragma unroll
            for (int r = 0; r < 4; ++r) {
                float xs = (kk == 0) ? xv[r].x : (kk == 1) ? xv[r].y : (kk == 2) ? xv[r].z : xv[r].w;
                acc[r][0] += xs * wv.x;
                acc[r][1] += xs * wv.y;
                acc[r][2] += xs * wv.z;
                acc[r][3] += xs * wv.w;
            }
        }
    }
#pragma unroll
    for (int r = 0; r < 4; ++r) {
        float4 o;
        o.x = acc[r][0]; o.y = acc[r][1]; o.z = acc[r][2]; o.w = acc[r][3];
        *(float4*)&h[(long)(r0 + rg * 4 + r) * FDIM + cg * 4] = o;
    }
}

// ---------------- out init: self-loop term + bias ----------------
__global__ void k_init_out(const float* __restrict__ h, const float* __restrict__ dinv,
                           const float* __restrict__ b1, float* __restrict__ out) {
    int idx = blockIdx.x * 256 + threadIdx.x;   // in float4 units
    if (idx >= N_NODES * (FDIM / 4)) return;
    int i = idx >> 5;
    int f4 = idx & 31;
    float d = dinv[i];
    float s = d * d;
    float4 hv = ((const float4*)h)[idx];
    float4 bv = ((const float4*)b1)[f4];
    float4 o;
    o.x = s * hv.x + bv.x;
    o.y = s * hv.y + bv.y;
    o.z = s * hv.z + bv.z;
    o.w = s * hv.w + bv.w;
    ((float4*)out)[idx] = o;
}

// ---------------- edge aggregation (atomic scatter) ----------------
__global__ void k_edge_agg(const int* __restrict__ src, const int* __restrict__ dst,
                           const float* __restrict__ h, const float* __restrict__ dinv,
                           float* __restrict__ out) {
    int idx = blockIdx.x * 256 + threadIdx.x;
    int e = idx >> 5;          // 32 threads per edge (float4 each)
    int f4 = idx & 31;
    if (e >= N_EDGES) return;
    int s = src[e];
    int d = dst[e];
    float norm = dinv[s] * dinv[d];
    float4 hv = ((const float4*)(h + (long)s * FDIM))[f4];
    float* op = out + (long)d * FDIM + f4 * 4;
    atomicAdd(op + 0, norm * hv.x);
    atomicAdd(op + 1, norm * hv.y);
    atomicAdd(op + 2, norm * hv.z);
    atomicAdd(op + 3, norm * hv.w);
}

// ---------------- per-graph max pool (relu folded) ----------------
__global__ void k_pool(const float* __restrict__ out, const int* __restrict__ batch,
                       float* __restrict__ pooled) {
    int g = blockIdx.x;
    int f = threadIdx.x;   // 128 threads
    int lo = 0, hi = N_NODES;
    while (lo < hi) { int mid = (lo + hi) >> 1; if (batch[mid] < g) lo = mid + 1; else hi = mid; }
    int start = lo;
    hi = N_NODES;
    while (lo < hi) { int mid = (lo + hi) >> 1; if (batch[mid] < g + 1) lo = mid + 1; else hi = mid; }
    int end = lo;
    float m = 0.0f;   // relu floor
    for (int i = start; i < end; ++i) m = fmaxf(m, out[(long)i * FDIM + f]);
    pooled[g * FDIM + f] = m;
}

// ---------------- head GEMM + log_softmax ----------------
__global__ void k_head(const float* __restrict__ pooled, const float* __restrict__ W2,
                       const float* __restrict__ b2, float* __restrict__ out) {
    int g = blockIdx.x;
    int lane = threadIdx.x;   // 64 threads, one wave
    int c = lane & 15;
    float acc = b2[c];
    for (int k = 0; k < FDIM; ++k) acc += pooled[g * FDIM + k] * W2[k * OUTF + c];
    float m = acc;
    for (int off = 1; off < 16; off <<= 1) m = fmaxf(m, __shfl_xor(m, off, 16));
    float s = expf(acc - m);
    for (int off = 1; off < 16; off <<= 1) s += __shfl_xor(s, off, 16);
    if (lane < 16) out[g * OUTF + c] = acc - m - logf(s);
}

extern "C" void kernel_launch(void* const* d_in, const int* in_sizes, int n_in,
                              void* d_out, int out_size, void* d_ws, size_t ws_size,
                              hipStream_t stream) {
    const float* x  = (const float*)d_in[0];
    const float* W1 = (const float*)d_in[1];
    const float* b1 = (const float*)d_in[2];
    const float* W2 = (const float*)d_in[3];
    const float* b2 = (const float*)d_in[4];
    const int* ei   = (const int*)d_in[5];
    const int* batch = (const int*)d_in[6];
    const int* src = ei;
    const int* dst = ei + N_EDGES;
    float* out = (float*)d_out;

    char* ws = (char*)d_ws;
    float* deg    = (float*)(ws + 0);                       // N floats (becomes dinv)
    float* h      = (float*)(ws + 400000);                  // N*128 floats
    float* outagg = (float*)(ws + 400000 + 51200000);       // N*128 floats
    float* pooled = (float*)(ws + 400000 + 2 * 51200000);   // 256*128 floats

    k_deg_init<<<(N_NODES + 255) / 256, 256, 0, stream>>>(deg);
    k_deg_edges<<<(N_EDGES + 255) / 256, 256, 0, stream>>>(dst, deg);
    k_dinv<<<(N_NODES + 255) / 256, 256, 0, stream>>>(deg);
    k_gemm<<<N_NODES / GR, 256, 0, stream>>>(x, W1, h);
    k_init_out<<<(N_NODES * 32 + 255) / 256, 256, 0, stream>>>(h, deg, b1, outagg);
    k_edge_agg<<<(N_EDGES * 32 + 255) / 256, 256, 0, stream>>>(src, dst, h, deg, outagg);
    k_pool<<<NGRAPH, FDIM, 0, stream>>>(outagg, batch, pooled);
    k_head<<<NGRAPH, 64, 0, stream>>>(pooled, W2, b2, out);
}

// Round 5
// 506.080 us; speedup vs baseline: 5.8738x; 5.8738x over previous
//
#include <hip/hip_runtime.h>

#define N_NODES 100000
#define N_EDGES 1600000
#define FDIM 128
#define OUTF 16
#define NGRAPH 256
#define SCAN_NB 98   // ceil(N_NODES/1024)

// ---------------- init: counts, cursor, pooled ----------------
__global__ void k_zero(int* __restrict__ counts, int* __restrict__ cursor,
                       float* __restrict__ pooled) {
    int i = blockIdx.x * 256 + threadIdx.x;
    if (i < N_NODES) { counts[i] = 0; cursor[i] = 0; }
    if (i < NGRAPH * FDIM) pooled[i] = 0.0f;
}

// ---------------- dst histogram (int atomics) ----------------
__global__ void k_hist(const int* __restrict__ dst, int* __restrict__ counts) {
    int e = blockIdx.x * 256 + threadIdx.x;
    if (e < N_EDGES) atomicAdd(&counts[dst[e]], 1);
}

// ---------------- dinv = rsqrt(deg), deg = counts + 1 (self-loop) ----------------
__global__ void k_dinv(const int* __restrict__ counts, float* __restrict__ dinv) {
    int i = blockIdx.x * 256 + threadIdx.x;
    if (i < N_NODES) dinv[i] = rsqrtf((float)counts[i] + 1.0f);
}

// ---------------- exclusive scan of counts -> row_start ----------------
__global__ void k_scan1(const int* __restrict__ counts, int* __restrict__ offs,
                        int* __restrict__ bsums) {
    __shared__ int tmp[256];
    int t = threadIdx.x;
    int base = blockIdx.x * 1024 + t * 4;
    int c[4]; int s = 0;
#pragma unroll
    for (int j = 0; j < 4; ++j) { c[j] = (base + j < N_NODES) ? counts[base + j] : 0; s += c[j]; }
    tmp[t] = s; __syncthreads();
    for (int off = 1; off < 256; off <<= 1) {
        int v = (t >= off) ? tmp[t - off] : 0;
        __syncthreads();
        tmp[t] += v;
        __syncthreads();
    }
    int run = tmp[t] - s;   // exclusive prefix of this thread's chunk within block
#pragma unroll
    for (int j = 0; j < 4; ++j) { if (base + j < N_NODES) offs[base + j] = run; run += c[j]; }
    if (t == 255) bsums[blockIdx.x] = tmp[255];
}

__global__ void k_scan2(int* __restrict__ bsums, int* __restrict__ offs) {
    if (threadIdx.x == 0) {
        int acc = 0;
        for (int i = 0; i < SCAN_NB; ++i) { int v = bsums[i]; bsums[i] = acc; acc += v; }
        offs[N_NODES] = N_EDGES;
    }
}

__global__ void k_scan3(int* __restrict__ offs, const int* __restrict__ bsums) {
    int t = threadIdx.x;
    int base = blockIdx.x * 1024 + t * 4;
    int add = bsums[blockIdx.x];
#pragma unroll
    for (int j = 0; j < 4; ++j) if (base + j < N_NODES) offs[base + j] += add;
}

// ---------------- scatter edges into CSR buckets ----------------
__global__ void k_scatter(const int* __restrict__ src, const int* __restrict__ dst,
                          const int* __restrict__ row_start, int* __restrict__ cursor,
                          int* __restrict__ csr_src) {
    int e = blockIdx.x * 256 + threadIdx.x;
    if (e >= N_EDGES) return;
    int d = dst[e];
    int pos = row_start[d] + atomicAdd(&cursor[d], 1);
    csr_src[pos] = src[e];
}

// ---------------- h = x @ W1 (fp32, LDS tiled, 4x4 register block) ----------------
#define GR 32
__launch_bounds__(256)
__global__ void k_gemm(const float* __restrict__ x, const float* __restrict__ W,
                       float* __restrict__ h) {
    __shared__ float Wl[128 * 128];
    __shared__ float Xl[GR][128];
    int t = threadIdx.x;

    const float4* W4 = (const float4*)W;
    float4* Wl4 = (float4*)Wl;
#pragma unroll
    for (int i = 0; i < 16; ++i) Wl4[t + i * 256] = W4[t + i * 256];

    int r0 = blockIdx.x * GR;
    const float4* X4 = (const float4*)(x + (long)r0 * FDIM);
    float4* Xl4 = (float4*)&Xl[0][0];
#pragma unroll
    for (int i = 0; i < 4; ++i) Xl4[t + i * 256] = X4[t + i * 256];
    __syncthreads();

    int cg = t & 31;
    int rg = t >> 5;
    float acc[4][4] = {};
    for (int k = 0; k < 128; k += 4) {
        float4 xv[4];
#pragma unroll
        for (int r = 0; r < 4; ++r) xv[r] = *(const float4*)&Xl[rg * 4 + r][k];
#pragma unroll
        for (int kk = 0; kk < 4; ++kk) {
            float4 wv = *(const float4*)&Wl[(k + kk) * 128 + cg * 4];
#pragma unroll
            for (int r = 0; r < 4; ++r) {
                float xs = (kk == 0) ? xv[r].x : (kk == 1) ? xv[r].y : (kk == 2) ? xv[r].z : xv[r].w;
                acc[r][0] += xs * wv.x;
                acc[r][1] += xs * wv.y;
                acc[r][2] += xs * wv.z;
                acc[r][3] += xs * wv.w;
            }
        }
    }
#pragma unroll
    for (int r = 0; r < 4; ++r) {
        float4 o;
        o.x = acc[r][0]; o.y = acc[r][1]; o.z = acc[r][2]; o.w = acc[r][3];
        *(float4*)&h[(long)(r0 + rg * 4 + r) * FDIM + cg * 4] = o;
    }
}

// ---------------- CSR gather-aggregate: out = dinv[d]*(dinv[d]*h[d] + sum dinv[s]*h[s]) + b1 ----------------
__launch_bounds__(256)
__global__ void k_agg(const float* __restrict__ h, const float* __restrict__ dinv,
                      const int* __restrict__ row_start, const int* __restrict__ csr_src,
                      const float* __restrict__ b1, float* __restrict__ out) {
    int t = threadIdx.x;
    int lane = t & 31;                    // float4 slot (128 feats / 4)
    int node = blockIdx.x * 8 + (t >> 5); // 8 nodes per block
    if (node >= N_NODES) return;
    float dd = dinv[node];
    float4 hv = ((const float4*)(h + (long)node * FDIM))[lane];
    float4 sum; sum.x = dd * hv.x; sum.y = dd * hv.y; sum.z = dd * hv.z; sum.w = dd * hv.w;
    int beg = row_start[node], end = row_start[node + 1];
    for (int j = beg; j < end; ++j) {
        int s = csr_src[j];
        float ds = dinv[s];
        float4 v = ((const float4*)(h + (long)s * FDIM))[lane];
        sum.x += ds * v.x; sum.y += ds * v.y; sum.z += ds * v.z; sum.w += ds * v.w;
    }
    float4 bv = ((const float4*)b1)[lane];
    float4 o;
    o.x = dd * sum.x + bv.x;
    o.y = dd * sum.y + bv.y;
    o.z = dd * sum.z + bv.z;
    o.w = dd * sum.w + bv.w;
    ((float4*)(out + (long)node * FDIM))[lane] = o;
}

// ---------------- pool: run-length max over sorted batch + int atomicMax (vals >= 0) ----------------
#define PNODES 64
__global__ void k_pool2(const float* __restrict__ out, const int* __restrict__ batch,
                        float* __restrict__ pooled) {
    int f = threadIdx.x;   // 128
    int r0 = blockIdx.x * PNODES;
    if (r0 >= N_NODES) return;
    int end = r0 + PNODES; if (end > N_NODES) end = N_NODES;
    float m = 0.0f;        // relu floor
    int gcur = batch[r0];
    for (int i = r0; i < end; ++i) {
        int g = batch[i];
        if (g != gcur) {
            atomicMax((int*)&pooled[gcur * FDIM + f], __float_as_int(m));
            m = 0.0f; gcur = g;
        }
        m = fmaxf(m, out[(long)i * FDIM + f]);
    }
    atomicMax((int*)&pooled[gcur * FDIM + f], __float_as_int(m));
}

// ---------------- head GEMM + log_softmax ----------------
__global__ void k_head(const float* __restrict__ pooled, const float* __restrict__ W2,
                       const float* __restrict__ b2, float* __restrict__ out) {
    int g = blockIdx.x;
    int lane = threadIdx.x;
    int c = lane & 15;
    float acc = b2[c];
    for (int k = 0; k < FDIM; ++k) acc += pooled[g * FDIM + k] * W2[k * OUTF + c];
    float m = acc;
    for (int off = 1; off < 16; off <<= 1) m = fmaxf(m, __shfl_xor(m, off, 16));
    float s = expf(acc - m);
    for (int off = 1; off < 16; off <<= 1) s += __shfl_xor(s, off, 16);
    if (lane < 16) out[g * OUTF + c] = acc - m - logf(s);
}

extern "C" void kernel_launch(void* const* d_in, const int* in_sizes, int n_in,
                              void* d_out, int out_size, void* d_ws, size_t ws_size,
                              hipStream_t stream) {
    const float* x  = (const float*)d_in[0];
    const float* W1 = (const float*)d_in[1];
    const float* b1 = (const float*)d_in[2];
    const float* W2 = (const float*)d_in[3];
    const float* b2 = (const float*)d_in[4];
    const int* ei   = (const int*)d_in[5];
    const int* batch = (const int*)d_in[6];
    const int* src = ei;
    const int* dst = ei + N_EDGES;
    float* out = (float*)d_out;

    char* ws = (char*)d_ws;
    float* dinv      = (float*)(ws + 0);           //  100000 f
    int*   counts    = (int*)  (ws + 400000);      //  100000 i
    int*   cursor    = (int*)  (ws + 800000);      //  100000 i
    int*   row_start = (int*)  (ws + 1200000);     //  100001 i
    int*   bsums     = (int*)  (ws + 1600512);     //  98 i
    float* pooled    = (float*)(ws + 1601024);     //  256*128 f
    int*   csr_src   = (int*)  (ws + 1732608);     //  1.6M i
    float* h         = (float*)(ws + 8132608);     //  N*128 f
    float* outagg    = (float*)(ws + 59332608);    //  N*128 f
    // total ~110.6 MB

    k_zero   <<<(N_NODES + 255) / 256, 256, 0, stream>>>(counts, cursor, pooled);
    k_hist   <<<(N_EDGES + 255) / 256, 256, 0, stream>>>(dst, counts);
    k_dinv   <<<(N_NODES + 255) / 256, 256, 0, stream>>>(counts, dinv);
    k_scan1  <<<SCAN_NB, 256, 0, stream>>>(counts, row_start, bsums);
    k_scan2  <<<1, 64, 0, stream>>>(bsums, row_start);
    k_scan3  <<<SCAN_NB, 256, 0, stream>>>(row_start, bsums);
    k_scatter<<<(N_EDGES + 255) / 256, 256, 0, stream>>>(src, dst, row_start, cursor, csr_src);
    k_gemm   <<<N_NODES / GR, 256, 0, stream>>>(x, W1, h);
    k_agg    <<<(N_NODES + 7) / 8, 256, 0, stream>>>(h, dinv, row_start, csr_src, b1, outagg);
    k_pool2  <<<(N_NODES + PNODES - 1) / PNODES, FDIM, 0, stream>>>(outagg, batch, pooled);
    k_head   <<<NGRAPH, 64, 0, stream>>>(pooled, W2, b2, out);
}

// Round 6
// 483.586 us; speedup vs baseline: 6.1470x; 1.0465x over previous
//
#include <hip/hip_runtime.h>

#define N_NODES 100000
#define N_EDGES 1600000
#define FDIM 128
#define OUTF 16
#define NGRAPH 256
#define SCAN_NB 98   // ceil(N_NODES/1024)

typedef unsigned int uint;
typedef unsigned short ushort;

__device__ inline uint pack_bf16(float a, float b) {
    uint ua = __float_as_uint(a); ua = (ua + 0x7fffu + ((ua >> 16) & 1u)) >> 16;
    uint ub = __float_as_uint(b); ub = (ub + 0x7fffu + ((ub >> 16) & 1u)) >> 16;
    return ua | (ub << 16);
}
__device__ inline void unpack_bf16(uint v, float& a, float& b) {
    a = __uint_as_float(v << 16);
    b = __uint_as_float(v & 0xffff0000u);
}

// ---------------- init: counts, pooled ----------------
__global__ void k_zero(int* __restrict__ counts, float* __restrict__ pooled) {
    int i = blockIdx.x * 256 + threadIdx.x;
    if (i < N_NODES) counts[i] = 0;
    if (i < NGRAPH * FDIM) pooled[i] = 0.0f;
}

// ---------------- dst histogram (int atomics) ----------------
__global__ void k_hist(const int* __restrict__ dst, int* __restrict__ counts) {
    int e = blockIdx.x * 256 + threadIdx.x;
    if (e < N_EDGES) atomicAdd(&counts[dst[e]], 1);
}

// ---------------- scan pass 1 (+ dinv fused) ----------------
__global__ void k_scan1(const int* __restrict__ counts, int* __restrict__ offs,
                        int* __restrict__ bsums, float* __restrict__ dinv) {
    __shared__ int tmp[256];
    int t = threadIdx.x;
    int base = blockIdx.x * 1024 + t * 4;
    int c[4]; int s = 0;
#pragma unroll
    for (int j = 0; j < 4; ++j) {
        c[j] = (base + j < N_NODES) ? counts[base + j] : 0;
        if (base + j < N_NODES) dinv[base + j] = rsqrtf((float)c[j] + 1.0f);
        s += c[j];
    }
    tmp[t] = s; __syncthreads();
    for (int off = 1; off < 256; off <<= 1) {
        int v = (t >= off) ? tmp[t - off] : 0;
        __syncthreads();
        tmp[t] += v;
        __syncthreads();
    }
    int run = tmp[t] - s;
#pragma unroll
    for (int j = 0; j < 4; ++j) { if (base + j < N_NODES) offs[base + j] = run; run += c[j]; }
    if (t == 255) bsums[blockIdx.x] = tmp[255];
}

__global__ void k_scan2(int* __restrict__ bsums, int* __restrict__ offs) {
    if (threadIdx.x == 0) {
        int acc = 0;
        for (int i = 0; i < SCAN_NB; ++i) { int v = bsums[i]; bsums[i] = acc; acc += v; }
        offs[N_NODES] = N_EDGES;
    }
}

// ---------------- scan pass 3: add block sums; also cursor = row_start ----------------
__global__ void k_scan3(int* __restrict__ offs, const int* __restrict__ bsums,
                        int* __restrict__ cursor) {
    int t = threadIdx.x;
    int base = blockIdx.x * 1024 + t * 4;
    int add = bsums[blockIdx.x];
#pragma unroll
    for (int j = 0; j < 4; ++j) {
        if (base + j < N_NODES) {
            int v = offs[base + j] + add;
            offs[base + j] = v;
            cursor[base + j] = v;
        }
    }
}

// ---------------- scatter edges into CSR buckets (single atomic, absolute slot) ----------------
__global__ void k_scatter(const int* __restrict__ src, const int* __restrict__ dst,
                          int* __restrict__ cursor, int* __restrict__ csr_src) {
    int e = blockIdx.x * 256 + threadIdx.x;
    if (e >= N_EDGES) return;
    int pos = atomicAdd(&cursor[dst[e]], 1);
    csr_src[pos] = src[e];
}

// ---------------- h = x @ W1 (fp32 accumulate, bf16 output) ----------------
#define GR 32
__launch_bounds__(256)
__global__ void k_gemm(const float* __restrict__ x, const float* __restrict__ W,
                       ushort* __restrict__ hbf) {
    __shared__ float Wl[128 * 128];
    __shared__ float Xl[GR][128];
    int t = threadIdx.x;

    const float4* W4 = (const float4*)W;
    float4* Wl4 = (float4*)Wl;
#pragma unroll
    for (int i = 0; i < 16; ++i) Wl4[t + i * 256] = W4[t + i * 256];

    int r0 = blockIdx.x * GR;
    const float4* X4 = (const float4*)(x + (long)r0 * FDIM);
    float4* Xl4 = (float4*)&Xl[0][0];
#pragma unroll
    for (int i = 0; i < 4; ++i) Xl4[t + i * 256] = X4[t + i * 256];
    __syncthreads();

    int cg = t & 31;
    int rg = t >> 5;
    float acc[4][4] = {};
    for (int k = 0; k < 128; k += 4) {
        float4 xv[4];
#pragma unroll
        for (int r = 0; r < 4; ++r) xv[r] = *(const float4*)&Xl[rg * 4 + r][k];
#pragma unroll
        for (int kk = 0; kk < 4; ++kk) {
            float4 wv = *(const float4*)&Wl[(k + kk) * 128 + cg * 4];
#pragma unroll
            for (int r = 0; r < 4; ++r) {
                float xs = (kk == 0) ? xv[r].x : (kk == 1) ? xv[r].y : (kk == 2) ? xv[r].z : xv[r].w;
                acc[r][0] += xs * wv.x;
                acc[r][1] += xs * wv.y;
                acc[r][2] += xs * wv.z;
                acc[r][3] += xs * wv.w;
            }
        }
    }
#pragma unroll
    for (int r = 0; r < 4; ++r) {
        uint2 p;
        p.x = pack_bf16(acc[r][0], acc[r][1]);
        p.y = pack_bf16(acc[r][2], acc[r][3]);
        *(uint2*)&hbf[(long)(r0 + rg * 4 + r) * FDIM + cg * 4] = p;
    }
}

// ---------------- CSR gather-aggregate (bf16 in / bf16 out) ----------------
__launch_bounds__(256)
__global__ void k_agg(const ushort* __restrict__ hbf, const float* __restrict__ dinv,
                      const int* __restrict__ row_start, const int* __restrict__ csr_src,
                      const float* __restrict__ b1, ushort* __restrict__ outbf) {
    int t = threadIdx.x;
    int lane = t & 31;                    // 4 feats per lane
    int node = blockIdx.x * 8 + (t >> 5); // 8 nodes per block (grid exact)
    const uint2* hb = (const uint2*)hbf;
    float dd = dinv[node];
    uint2 v = hb[node * 32 + lane];
    float f0, f1, f2, f3;
    unpack_bf16(v.x, f0, f1); unpack_bf16(v.y, f2, f3);
    float s0 = dd * f0, s1 = dd * f1, s2 = dd * f2, s3 = dd * f3;
    int beg = row_start[node], end = row_start[node + 1];
    int j = beg;
    for (; j + 1 < end; j += 2) {
        int sa = csr_src[j], sb = csr_src[j + 1];
        float da = dinv[sa], db = dinv[sb];
        uint2 va = hb[sa * 32 + lane];
        uint2 vb = hb[sb * 32 + lane];
        float a0, a1, a2, a3, c0, c1, c2, c3;
        unpack_bf16(va.x, a0, a1); unpack_bf16(va.y, a2, a3);
        unpack_bf16(vb.x, c0, c1); unpack_bf16(vb.y, c2, c3);
        s0 += da * a0 + db * c0;
        s1 += da * a1 + db * c1;
        s2 += da * a2 + db * c2;
        s3 += da * a3 + db * c3;
    }
    if (j < end) {
        int sa = csr_src[j];
        float da = dinv[sa];
        uint2 va = hb[sa * 32 + lane];
        float a0, a1, a2, a3;
        unpack_bf16(va.x, a0, a1); unpack_bf16(va.y, a2, a3);
        s0 += da * a0; s1 += da * a1; s2 += da * a2; s3 += da * a3;
    }
    float4 bv = ((const float4*)b1)[lane];
    uint2 o;
    o.x = pack_bf16(dd * s0 + bv.x, dd * s1 + bv.y);
    o.y = pack_bf16(dd * s2 + bv.z, dd * s3 + bv.w);
    ((uint2*)outbf)[node * 32 + lane] = o;
}

// ---------------- pool: run-length max over sorted batch + int atomicMax (vals >= 0) ----------------
#define PNODES 64
__global__ void k_pool2(const ushort* __restrict__ outbf, const int* __restrict__ batch,
                        float* __restrict__ pooled) {
    int f = threadIdx.x;   // 128
    int r0 = blockIdx.x * PNODES;
    if (r0 >= N_NODES) return;
    int end = r0 + PNODES; if (end > N_NODES) end = N_NODES;
    float m = 0.0f;        // relu floor
    int gcur = batch[r0];
    for (int i = r0; i < end; ++i) {
        int g = batch[i];
        if (g != gcur) {
            atomicMax((int*)&pooled[gcur * FDIM + f], __float_as_int(m));
            m = 0.0f; gcur = g;
        }
        uint u = outbf[(long)i * FDIM + f];
        m = fmaxf(m, __uint_as_float(u << 16));
    }
    atomicMax((int*)&pooled[gcur * FDIM + f], __float_as_int(m));
}

// ---------------- head GEMM + log_softmax ----------------
__global__ void k_head(const float* __restrict__ pooled, const float* __restrict__ W2,
                       const float* __restrict__ b2, float* __restrict__ out) {
    int g = blockIdx.x;
    int lane = threadIdx.x;
    int c = lane & 15;
    float acc = b2[c];
    for (int k = 0; k < FDIM; ++k) acc += pooled[g * FDIM + k] * W2[k * OUTF + c];
    float m = acc;
    for (int off = 1; off < 16; off <<= 1) m = fmaxf(m, __shfl_xor(m, off, 16));
    float s = expf(acc - m);
    for (int off = 1; off < 16; off <<= 1) s += __shfl_xor(s, off, 16);
    if (lane < 16) out[g * OUTF + c] = acc - m - logf(s);
}

extern "C" void kernel_launch(void* const* d_in, const int* in_sizes, int n_in,
                              void* d_out, int out_size, void* d_ws, size_t ws_size,
                              hipStream_t stream) {
    const float* x  = (const float*)d_in[0];
    const float* W1 = (const float*)d_in[1];
    const float* b1 = (const float*)d_in[2];
    const float* W2 = (const float*)d_in[3];
    const float* b2 = (const float*)d_in[4];
    const int* ei   = (const int*)d_in[5];
    const int* batch = (const int*)d_in[6];
    const int* src = ei;
    const int* dst = ei + N_EDGES;
    float* out = (float*)d_out;

    char* ws = (char*)d_ws;
    float*  dinv      = (float*) (ws + 0);           //  100000 f
    int*    counts    = (int*)   (ws + 400000);      //  100000 i
    int*    cursor    = (int*)   (ws + 800000);      //  100000 i
    int*    row_start = (int*)   (ws + 1200000);     //  100001 i
    int*    bsums     = (int*)   (ws + 1600512);     //  98 i
    float*  pooled    = (float*) (ws + 1601024);     //  256*128 f
    int*    csr_src   = (int*)   (ws + 1732608);     //  1.6M i
    ushort* hbf       = (ushort*)(ws + 8132608);     //  N*128 bf16 (25.6 MB)
    ushort* outbf     = (ushort*)(ws + 33732608);    //  N*128 bf16 (25.6 MB)
    // total ~59.3 MB

    k_zero   <<<(N_NODES + 255) / 256, 256, 0, stream>>>(counts, pooled);
    k_hist   <<<(N_EDGES + 255) / 256, 256, 0, stream>>>(dst, counts);
    k_scan1  <<<SCAN_NB, 256, 0, stream>>>(counts, row_start, bsums, dinv);
    k_scan2  <<<1, 64, 0, stream>>>(bsums, row_start);
    k_scan3  <<<SCAN_NB, 256, 0, stream>>>(row_start, bsums, cursor);
    k_scatter<<<(N_EDGES + 255) / 256, 256, 0, stream>>>(src, dst, cursor, csr_src);
    k_gemm   <<<N_NODES / GR, 256, 0, stream>>>(x, W1, hbf);
    k_agg    <<<N_NODES / 8, 256, 0, stream>>>(hbf, dinv, row_start, csr_src, b1, outbf);
    k_pool2  <<<(N_NODES + PNODES - 1) / PNODES, FDIM, 0, stream>>>(outbf, batch, pooled);
    k_head   <<<NGRAPH, 64, 0, stream>>>(pooled, W2, b2, out);
}

// Round 8
// 361.109 us; speedup vs baseline: 8.2319x; 1.3392x over previous
//
#include <hip/hip_runtime.h>

#define N_NODES 100000
#define N_EDGES 1600000
#define FDIM 128
#define OUTF 16
#define NGRAPH 256

#define NBLK 512          // partition blocks
#define CHUNK 3125        // N_EDGES / NBLK (exact)
#define NB_BUCKET 391     // ceil(N_NODES/256), bucket = dst >> 8
#define BC_N (NB_BUCKET * NBLK)   // 200192
#define BC_SCAN_NB 196    // ceil(BC_N/1024)

typedef unsigned int uint;
typedef unsigned short ushort;

__device__ inline uint pack_bf16(float a, float b) {
    uint ua = __float_as_uint(a); ua = (ua + 0x7fffu + ((ua >> 16) & 1u)) >> 16;
    uint ub = __float_as_uint(b); ub = (ub + 0x7fffu + ((ub >> 16) & 1u)) >> 16;
    return ua | (ub << 16);
}
__device__ inline void unpack_bf16(uint v, float& a, float& b) {
    a = __uint_as_float(v << 16);
    b = __uint_as_float(v & 0xffff0000u);
}

// ---------------- zero pooled, seal row_start ----------------
__global__ void k_zero(float* __restrict__ pooled, int* __restrict__ row_start) {
    int i = blockIdx.x * 256 + threadIdx.x;
    if (i < NGRAPH * FDIM) pooled[i] = 0.0f;
    if (i == 0) row_start[N_NODES] = N_EDGES;
}

// ---------------- pass A: per-block bucket histogram (LDS atomics only) ----------------
__launch_bounds__(256)
__global__ void k_bhist(const int* __restrict__ dst, int* __restrict__ bcount) {
    __shared__ int hist[NB_BUCKET];
    int t = threadIdx.x, blk = blockIdx.x;
    for (int i = t; i < NB_BUCKET; i += 256) hist[i] = 0;
    __syncthreads();
    int base = blk * CHUNK;
    for (int j = t; j < CHUNK; j += 256) atomicAdd(&hist[dst[base + j] >> 8], 1);
    __syncthreads();
    for (int i = t; i < NB_BUCKET; i += 256) bcount[i * NBLK + blk] = hist[i];
}

// ---------------- generic exclusive scan (3 kernels) ----------------
__global__ void k_scan1g(const int* __restrict__ in, int* __restrict__ offs,
                         int* __restrict__ bsums, int n) {
    __shared__ int tmp[256];
    int t = threadIdx.x;
    int base = blockIdx.x * 1024 + t * 4;
    int c[4]; int s = 0;
#pragma unroll
    for (int j = 0; j < 4; ++j) { c[j] = (base + j < n) ? in[base + j] : 0; s += c[j]; }
    tmp[t] = s; __syncthreads();
    for (int off = 1; off < 256; off <<= 1) {
        int v = (t >= off) ? tmp[t - off] : 0;
        __syncthreads();
        tmp[t] += v;
        __syncthreads();
    }
    int run = tmp[t] - s;
#pragma unroll
    for (int j = 0; j < 4; ++j) { if (base + j < n) offs[base + j] = run; run += c[j]; }
    if (t == 255) bsums[blockIdx.x] = tmp[255];
}

__global__ void k_scan2g(int* __restrict__ bsums, int* __restrict__ offs,
                         int nb, int n, int total) {
    if (threadIdx.x == 0) {
        int acc = 0;
        for (int i = 0; i < nb; ++i) { int v = bsums[i]; bsums[i] = acc; acc += v; }
        offs[n] = total;
    }
}

__global__ void k_scan3g(int* __restrict__ offs, const int* __restrict__ bsums, int n) {
    int t = threadIdx.x;
    int base = blockIdx.x * 1024 + t * 4;
    int add = bsums[blockIdx.x];
#pragma unroll
    for (int j = 0; j < 4; ++j) if (base + j < n) offs[base + j] += add;
}

// ---------------- pass B: partition edges into bucket regions (no global atomics) ----------------
__launch_bounds__(256)
__global__ void k_bucket(const int* __restrict__ src, const int* __restrict__ dst,
                         const int* __restrict__ boff, int2* __restrict__ ebuf) {
    __shared__ int cur[NB_BUCKET];
    int t = threadIdx.x, blk = blockIdx.x;
    for (int i = t; i < NB_BUCKET; i += 256) cur[i] = boff[i * NBLK + blk];
    __syncthreads();
    int base = blk * CHUNK;
    for (int j = t; j < CHUNK; j += 256) {
        int d = dst[base + j], s = src[base + j];
        int pos = atomicAdd(&cur[d >> 8], 1);
        ebuf[pos] = make_int2(d, s);
    }
}

// ---------------- pass C: per-bucket node count + LDS scan -> row_start, dinv, csr ----------------
__launch_bounds__(256)
__global__ void k_build(const int2* __restrict__ ebuf, const int* __restrict__ boff,
                        int* __restrict__ row_start, float* __restrict__ dinv,
                        int* __restrict__ csr_src) {
    __shared__ int cnt[256], sh[256], cur[256];
    int t = threadIdx.x, b = blockIdx.x;
    int bstart = boff[b * NBLK];
    int bend   = boff[(b + 1) * NBLK];   // boff[BC_N] = N_EDGES for last bucket
    cnt[t] = 0;
    __syncthreads();
    for (int j = bstart + t; j < bend; j += 256)
        atomicAdd(&cnt[ebuf[j].x & 255], 1);
    __syncthreads();
    int c = cnt[t];
    sh[t] = c;
    __syncthreads();
    for (int o = 1; o < 256; o <<= 1) {
        int v = (t >= o) ? sh[t - o] : 0;
        __syncthreads();
        sh[t] += v;
        __syncthreads();
    }
    int rs = bstart + sh[t] - c;   // exclusive prefix within bucket
    cur[t] = rs;
    int node = b * 256 + t;
    if (node < N_NODES) {
        row_start[node] = rs;
        dinv[node] = rsqrtf((float)c + 1.0f);
    }
    __syncthreads();
    for (int j = bstart + t; j < bend; j += 256) {
        int2 e = ebuf[j];
        int pos = atomicAdd(&cur[e.x & 255], 1);
        csr_src[pos] = e.y;
    }
}

// ---------------- h = x @ W1 (fp32 accumulate, bf16 output) ----------------
#define GR 32
__launch_bounds__(256)
__global__ void k_gemm(const float* __restrict__ x, const float* __restrict__ W,
                       ushort* __restrict__ hbf) {
    __shared__ float Wl[128 * 128];
    __shared__ float Xl[GR][128];
    int t = threadIdx.x;

    const float4* W4 = (const float4*)W;
    float4* Wl4 = (float4*)Wl;
#pragma unroll
    for (int i = 0; i < 16; ++i) Wl4[t + i * 256] = W4[t + i * 256];

    int r0 = blockIdx.x * GR;
    const float4* X4 = (const float4*)(x + (long)r0 * FDIM);
    float4* Xl4 = (float4*)&Xl[0][0];
#pragma unroll
    for (int i = 0; i < 4; ++i) Xl4[t + i * 256] = X4[t + i * 256];
    __syncthreads();

    int cg = t & 31;
    int rg = t >> 5;
    float acc[4][4] = {};
    for (int k = 0; k < 128; k += 4) {
        float4 xv[4];
#pragma unroll
        for (int r = 0; r < 4; ++r) xv[r] = *(const float4*)&Xl[rg * 4 + r][k];
#pragma unroll
        for (int kk = 0; kk < 4; ++kk) {
            float4 wv = *(const float4*)&Wl[(k + kk) * 128 + cg * 4];
#pragma unroll
            for (int r = 0; r < 4; ++r) {
                float xs = (kk == 0) ? xv[r].x : (kk == 1) ? xv[r].y : (kk == 2) ? xv[r].z : xv[r].w;
                acc[r][0] += xs * wv.x;
                acc[r][1] += xs * wv.y;
                acc[r][2] += xs * wv.z;
                acc[r][3] += xs * wv.w;
            }
        }
    }
#pragma unroll
    for (int r = 0; r < 4; ++r) {
        uint2 p;
        p.x = pack_bf16(acc[r][0], acc[r][1]);
        p.y = pack_bf16(acc[r][2], acc[r][3]);
        *(uint2*)&hbf[(long)(r0 + rg * 4 + r) * FDIM + cg * 4] = p;
    }
}

// ---------------- CSR gather-aggregate (bf16 in / bf16 out) ----------------
__launch_bounds__(256)
__global__ void k_agg(const ushort* __restrict__ hbf, const float* __restrict__ dinv,
                      const int* __restrict__ row_start, const int* __restrict__ csr_src,
                      const float* __restrict__ b1, ushort* __restrict__ outbf) {
    int t = threadIdx.x;
    int lane = t & 31;                    // 4 feats per lane
    int node = blockIdx.x * 8 + (t >> 5); // 8 nodes per block (grid exact)
    const uint2* hb = (const uint2*)hbf;
    float dd = dinv[node];
    uint2 v = hb[node * 32 + lane];
    float f0, f1, f2, f3;
    unpack_bf16(v.x, f0, f1); unpack_bf16(v.y, f2, f3);
    float s0 = dd * f0, s1 = dd * f1, s2 = dd * f2, s3 = dd * f3;
    int beg = row_start[node], end = row_start[node + 1];
    int j = beg;
    for (; j + 1 < end; j += 2) {
        int sa = csr_src[j], sb = csr_src[j + 1];
        float da = dinv[sa], db = dinv[sb];
        uint2 va = hb[sa * 32 + lane];
        uint2 vb = hb[sb * 32 + lane];
        float a0, a1, a2, a3, c0, c1, c2, c3;
        unpack_bf16(va.x, a0, a1); unpack_bf16(va.y, a2, a3);
        unpack_bf16(vb.x, c0, c1); unpack_bf16(vb.y, c2, c3);
        s0 += da * a0 + db * c0;
        s1 += da * a1 + db * c1;
        s2 += da * a2 + db * c2;
        s3 += da * a3 + db * c3;
    }
    if (j < end) {
        int sa = csr_src[j];
        float da = dinv[sa];
        uint2 va = hb[sa * 32 + lane];
        float a0, a1, a2, a3;
        unpack_bf16(va.x, a0, a1); unpack_bf16(va.y, a2, a3);
        s0 += da * a0; s1 += da * a1; s2 += da * a2; s3 += da * a3;
    }
    float4 bv = ((const float4*)b1)[lane];
    uint2 o;
    o.x = pack_bf16(dd * s0 + bv.x, dd * s1 + bv.y);
    o.y = pack_bf16(dd * s2 + bv.z, dd * s3 + bv.w);
    ((uint2*)outbf)[node * 32 + lane] = o;
}

// ---------------- pool: run-length max over sorted batch + int atomicMax (vals >= 0) ----------------
#define PNODES 64
__global__ void k_pool2(const ushort* __restrict__ outbf, const int* __restrict__ batch,
                        float* __restrict__ pooled) {
    int f = threadIdx.x;   // 128
    int r0 = blockIdx.x * PNODES;
    if (r0 >= N_NODES) return;
    int end = r0 + PNODES; if (end > N_NODES) end = N_NODES;
    float m = 0.0f;        // relu floor
    int gcur = batch[r0];
    for (int i = r0; i < end; ++i) {
        int g = batch[i];
        if (g != gcur) {
            atomicMax((int*)&pooled[gcur * FDIM + f], __float_as_int(m));
            m = 0.0f; gcur = g;
        }
        uint u = outbf[(long)i * FDIM + f];
        m = fmaxf(m, __uint_as_float(u << 16));
    }
    atomicMax((int*)&pooled[gcur * FDIM + f], __float_as_int(m));
}

// ---------------- head GEMM + log_softmax ----------------
__global__ void k_head(const float* __restrict__ pooled, const float* __restrict__ W2,
                       const float* __restrict__ b2, float* __restrict__ out) {
    int g = blockIdx.x;
    int lane = threadIdx.x;
    int c = lane & 15;
    float acc = b2[c];
    for (int k = 0; k < FDIM; ++k) acc += pooled[g * FDIM + k] * W2[k * OUTF + c];
    float m = acc;
    for (int off = 1; off < 16; off <<= 1) m = fmaxf(m, __shfl_xor(m, off, 16));
    float s = expf(acc - m);
    for (int off = 1; off < 16; off <<= 1) s += __shfl_xor(s, off, 16);
    if (lane < 16) out[g * OUTF + c] = acc - m - logf(s);
}

extern "C" void kernel_launch(void* const* d_in, const int* in_sizes, int n_in,
                              void* d_out, int out_size, void* d_ws, size_t ws_size,
                              hipStream_t stream) {
    const float* x  = (const float*)d_in[0];
    const float* W1 = (const float*)d_in[1];
    const float* b1 = (const float*)d_in[2];
    const float* W2 = (const float*)d_in[3];
    const float* b2 = (const float*)d_in[4];
    const int* ei   = (const int*)d_in[5];
    const int* batch = (const int*)d_in[6];
    const int* src = ei;
    const int* dst = ei + N_EDGES;
    float* out = (float*)d_out;

    char* ws = (char*)d_ws;
    float*  dinv      = (float*) (ws + 0);          // 100000 f
    int*    row_start = (int*)   (ws + 400000);     // 100001 i
    float*  pooled    = (float*) (ws + 800064);     // 32768 f
    int*    bcount    = (int*)   (ws + 931200);     // BC_N i (800768 B)
    int*    boff      = (int*)   (ws + 1732032);    // BC_N+1 i (800772 B)
    int*    bsums     = (int*)   (ws + 2532864);    // 196 i
    int*    csr_src   = (int*)   (ws + 2533696);    // 1.6M i (6.4 MB)
    int2*   ebuf      = (int2*)  (ws + 8933696);    // 1.6M int2 (12.8 MB)
    ushort* hbf       = (ushort*)(ws + 21733696);   // N*128 bf16 (25.6 MB)
    ushort* outbf     = (ushort*)(ws + 47333696);   // N*128 bf16 (25.6 MB)
    // total ~72.9 MB

    k_zero   <<<128, 256, 0, stream>>>(pooled, row_start);
    k_bhist  <<<NBLK, 256, 0, stream>>>(dst, bcount);
    k_scan1g <<<BC_SCAN_NB, 256, 0, stream>>>(bcount, boff, bsums, BC_N);
    k_scan2g <<<1, 64, 0, stream>>>(bsums, boff, BC_SCAN_NB, BC_N, N_EDGES);
    k_scan3g <<<BC_SCAN_NB, 256, 0, stream>>>(boff, bsums, BC_N);
    k_bucket <<<NBLK, 256, 0, stream>>>(src, dst, boff, ebuf);
    k_build  <<<NB_BUCKET, 256, 0, stream>>>(ebuf, boff, row_start, dinv, csr_src);
    k_gemm   <<<N_NODES / GR, 256, 0, stream>>>(x, W1, hbf);
    k_agg    <<<N_NODES / 8, 256, 0, stream>>>(hbf, dinv, row_start, csr_src, b1, outbf);
    k_pool2  <<<(N_NODES + PNODES - 1) / PNODES, FDIM, 0, stream>>>(outbf, batch, pooled);
    k_head   <<<NGRAPH, 64, 0, stream>>>(pooled, W2, b2, out);
}

// Round 13
// 296.222 us; speedup vs baseline: 10.0350x; 1.2190x over previous
//
#include <hip/hip_runtime.h>

#define N_NODES 100000
#define N_EDGES 1600000
#define FDIM 128
#define OUTF 16
#define NGRAPH 256

#define NBLK 512          // partition blocks
#define CHUNK 3125        // N_EDGES / NBLK (exact)
#define NB_BUCKET 391     // ceil(N_NODES/256), bucket = dst >> 8
#define BC_N (NB_BUCKET * NBLK)   // 200192
#define BC_SCAN_NB 196    // ceil(BC_N/1024)

typedef unsigned int uint;
typedef unsigned short ushort;
typedef short bf16x8 __attribute__((ext_vector_type(8)));   // 8 bf16 in 4 VGPRs (guide §3)
typedef float f32x4 __attribute__((ext_vector_type(4)));

__device__ inline uint pack_bf16(float a, float b) {
    uint ua = __float_as_uint(a); ua = (ua + 0x7fffu + ((ua >> 16) & 1u)) >> 16;
    uint ub = __float_as_uint(b); ub = (ub + 0x7fffu + ((ub >> 16) & 1u)) >> 16;
    return ua | (ub << 16);
}
__device__ inline ushort bf16_1(float a) {
    uint u = __float_as_uint(a);
    return (ushort)((u + 0x7fffu + ((u >> 16) & 1u)) >> 16);
}
__device__ inline void unpack_bf16(uint v, float& a, float& b) {
    a = __uint_as_float(v << 16);
    b = __uint_as_float(v & 0xffff0000u);
}

// ---------------- zero pooled, seal row_start ----------------
__global__ void k_zero(float* __restrict__ pooled, int* __restrict__ row_start) {
    int i = blockIdx.x * 256 + threadIdx.x;
    if (i < NGRAPH * FDIM) pooled[i] = 0.0f;
    if (i == 0) row_start[N_NODES] = N_EDGES;
}

// ---------------- pass A: per-block bucket histogram (LDS atomics only) ----------------
__launch_bounds__(256)
__global__ void k_bhist(const int* __restrict__ dst, int* __restrict__ bcount) {
    __shared__ int hist[NB_BUCKET];
    int t = threadIdx.x, blk = blockIdx.x;
    for (int i = t; i < NB_BUCKET; i += 256) hist[i] = 0;
    __syncthreads();
    int base = blk * CHUNK;
    for (int j = t; j < CHUNK; j += 256) atomicAdd(&hist[dst[base + j] >> 8], 1);
    __syncthreads();
    for (int i = t; i < NB_BUCKET; i += 256) bcount[i * NBLK + blk] = hist[i];
}

// ---------------- generic exclusive scan (3 kernels) ----------------
__global__ void k_scan1g(const int* __restrict__ in, int* __restrict__ offs,
                         int* __restrict__ bsums, int n) {
    __shared__ int tmp[256];
    int t = threadIdx.x;
    int base = blockIdx.x * 1024 + t * 4;
    int c[4]; int s = 0;
#pragma unroll
    for (int j = 0; j < 4; ++j) { c[j] = (base + j < n) ? in[base + j] : 0; s += c[j]; }
    tmp[t] = s; __syncthreads();
    for (int off = 1; off < 256; off <<= 1) {
        int v = (t >= off) ? tmp[t - off] : 0;
        __syncthreads();
        tmp[t] += v;
        __syncthreads();
    }
    int run = tmp[t] - s;
#pragma unroll
    for (int j = 0; j < 4; ++j) { if (base + j < n) offs[base + j] = run; run += c[j]; }
    if (t == 255) bsums[blockIdx.x] = tmp[255];
}

__global__ void k_scan2g(int* __restrict__ bsums, int* __restrict__ offs,
                         int nb, int n, int total) {
    if (threadIdx.x == 0) {
        int acc = 0;
        for (int i = 0; i < nb; ++i) { int v = bsums[i]; bsums[i] = acc; acc += v; }
        offs[n] = total;
    }
}

__global__ void k_scan3g(int* __restrict__ offs, const int* __restrict__ bsums, int n) {
    int t = threadIdx.x;
    int base = blockIdx.x * 1024 + t * 4;
    int add = bsums[blockIdx.x];
#pragma unroll
    for (int j = 0; j < 4; ++j) if (base + j < n) offs[base + j] += add;
}

// ---------------- pass B: partition edges into bucket regions (no global atomics) ----------------
__launch_bounds__(256)
__global__ void k_bucket(const int* __restrict__ src, const int* __restrict__ dst,
                         const int* __restrict__ boff, int2* __restrict__ ebuf) {
    __shared__ int cur[NB_BUCKET];
    int t = threadIdx.x, blk = blockIdx.x;
    for (int i = t; i < NB_BUCKET; i += 256) cur[i] = boff[i * NBLK + blk];
    __syncthreads();
    int base = blk * CHUNK;
    for (int j = t; j < CHUNK; j += 256) {
        int d = dst[base + j], s = src[base + j];
        int pos = atomicAdd(&cur[d >> 8], 1);
        ebuf[pos] = make_int2(d, s);
    }
}

// ---------------- pass C: per-bucket node count + LDS scan -> row_start, dinv, csr ----------------
__launch_bounds__(256)
__global__ void k_build(const int2* __restrict__ ebuf, const int* __restrict__ boff,
                        int* __restrict__ row_start, float* __restrict__ dinv,
                        int* __restrict__ csr_src) {
    __shared__ int cnt[256], sh[256], cur[256];
    int t = threadIdx.x, b = blockIdx.x;
    int bstart = boff[b * NBLK];
    int bend   = boff[(b + 1) * NBLK];   // boff[BC_N] = N_EDGES for last bucket
    cnt[t] = 0;
    __syncthreads();
    for (int j = bstart + t; j < bend; j += 256)
        atomicAdd(&cnt[ebuf[j].x & 255], 1);
    __syncthreads();
    int c = cnt[t];
    sh[t] = c;
    __syncthreads();
    for (int o = 1; o < 256; o <<= 1) {
        int v = (t >= o) ? sh[t - o] : 0;
        __syncthreads();
        sh[t] += v;
        __syncthreads();
    }
    int rs = bstart + sh[t] - c;   // exclusive prefix within bucket
    cur[t] = rs;
    int node = b * 256 + t;
    if (node < N_NODES) {
        row_start[node] = rs;
        dinv[node] = rsqrtf((float)c + 1.0f);
    }
    __syncthreads();
    for (int j = bstart + t; j < bend; j += 256) {
        int2 e = ebuf[j];
        int pos = atomicAdd(&cur[e.x & 255], 1);
        csr_src[pos] = e.y;
    }
}

// ---------------- W transpose + cast: Wt[col][k] = bf16(W1[k][col]) ----------------
__global__ void k_wcast(const float* __restrict__ W, ushort* __restrict__ wt) {
    int i = blockIdx.x * 256 + threadIdx.x;   // 16384 total
    int col = i >> 7, k = i & 127;
    wt[col * 128 + k] = bf16_1(W[k * 128 + col]);
}

// ---------------- h = x @ W1 via bf16 MFMA (fp32 acc, bf16 out) ----------------
#define BM 128
#define LDP 136   // padded row (shorts): 272 B stride -> 2-way bank aliasing (free)
__launch_bounds__(256)
__global__ void k_gemm(const float* __restrict__ x, const ushort* __restrict__ wt,
                       ushort* __restrict__ hbf) {
    __shared__ ushort AL[BM][LDP];
    __shared__ ushort WL[128][LDP];
    int t = threadIdx.x;
    int r0 = blockIdx.x * BM;

    // stage Wt (bf16) into LDS
    for (int i = t; i < 128 * 16; i += 256) {
        int r = i >> 4, s = i & 15;
        *(uint4*)&WL[r][s * 8] = *(const uint4*)&wt[r * 128 + s * 8];
    }
    // stage A tile: fp32 -> bf16
    {
        int r = t >> 1, half = t & 1;
        int grow = r0 + r; if (grow >= N_NODES) grow = N_NODES - 1;
        const float4* xp = (const float4*)(x + (long)grow * FDIM + half * 64);
        ushort* ap = &AL[r][half * 64];
#pragma unroll
        for (int i = 0; i < 16; ++i) {
            float4 v = xp[i];
            uint2 p;
            p.x = pack_bf16(v.x, v.y);
            p.y = pack_bf16(v.z, v.w);
            *(uint2*)&ap[i * 4] = p;
        }
    }
    __syncthreads();

    int w = t >> 6, l = t & 63;
    int lr = l & 15;            // row-within-tile for A, col-within-tile for B
    int lk = (l >> 4) * 8;      // k-slice base
    f32x4 acc[2][8] = {};
#pragma unroll
    for (int kc = 0; kc < 4; ++kc) {
        int ko = kc * 32 + lk;
        bf16x8 a0 = *(const bf16x8*)&AL[w * 32 + lr][ko];
        bf16x8 a1 = *(const bf16x8*)&AL[w * 32 + 16 + lr][ko];
        bf16x8 b[8];
#pragma unroll
        for (int ct = 0; ct < 8; ++ct) b[ct] = *(const bf16x8*)&WL[ct * 16 + lr][ko];
#pragma unroll
        for (int ct = 0; ct < 8; ++ct) {
            acc[0][ct] = __builtin_amdgcn_mfma_f32_16x16x32_bf16(a0, b[ct], acc[0][ct], 0, 0, 0);
            acc[1][ct] = __builtin_amdgcn_mfma_f32_16x16x32_bf16(a1, b[ct], acc[1][ct], 0, 0, 0);
        }
    }
    // epilogue: C/D layout col=lane&15, row=(lane>>4)*4+reg  [m89-verified]
    int rbase = r0 + w * 32 + (l >> 4) * 4;
#pragma unroll
    for (int rt = 0; rt < 2; ++rt) {
#pragma unroll
        for (int ct = 0; ct < 8; ++ct) {
#pragma unroll
            for (int reg = 0; reg < 4; ++reg) {
                int row = rbase + rt * 16 + reg;
                if (row < N_NODES)
                    hbf[(long)row * FDIM + ct * 16 + lr] = bf16_1(acc[rt][ct][reg]);
            }
        }
    }
}

// ---------------- CSR gather-aggregate (bf16 in / bf16 out) ----------------
__launch_bounds__(256)
__global__ void k_agg(const ushort* __restrict__ hbf, const float* __restrict__ dinv,
                      const int* __restrict__ row_start, const int* __restrict__ csr_src,
                      const float* __restrict__ b1, ushort* __restrict__ outbf) {
    int t = threadIdx.x;
    int lane = t & 31;                    // 4 feats per lane
    int node = blockIdx.x * 8 + (t >> 5); // 8 nodes per block (grid exact)
    const uint2* hb = (const uint2*)hbf;
    float dd = dinv[node];
    uint2 v = hb[node * 32 + lane];
    float f0, f1, f2, f3;
    unpack_bf16(v.x, f0, f1); unpack_bf16(v.y, f2, f3);
    float s0 = dd * f0, s1 = dd * f1, s2 = dd * f2, s3 = dd * f3;
    int beg = row_start[node], end = row_start[node + 1];
    int j = beg;
    for (; j + 1 < end; j += 2) {
        int sa = csr_src[j], sb = csr_src[j + 1];
        float da = dinv[sa], db = dinv[sb];
        uint2 va = hb[sa * 32 + lane];
        uint2 vb = hb[sb * 32 + lane];
        float a0, a1, a2, a3, c0, c1, c2, c3;
        unpack_bf16(va.x, a0, a1); unpack_bf16(va.y, a2, a3);
        unpack_bf16(vb.x, c0, c1); unpack_bf16(vb.y, c2, c3);
        s0 += da * a0 + db * c0;
        s1 += da * a1 + db * c1;
        s2 += da * a2 + db * c2;
        s3 += da * a3 + db * c3;
    }
    if (j < end) {
        int sa = csr_src[j];
        float da = dinv[sa];
        uint2 va = hb[sa * 32 + lane];
        float a0, a1, a2, a3;
        unpack_bf16(va.x, a0, a1); unpack_bf16(va.y, a2, a3);
        s0 += da * a0; s1 += da * a1; s2 += da * a2; s3 += da * a3;
    }
    float4 bv = ((const float4*)b1)[lane];
    uint2 o;
    o.x = pack_bf16(dd * s0 + bv.x, dd * s1 + bv.y);
    o.y = pack_bf16(dd * s2 + bv.z, dd * s3 + bv.w);
    ((uint2*)outbf)[node * 32 + lane] = o;
}

// ---------------- pool: run-length max over sorted batch + int atomicMax (vals >= 0) ----------------
#define PNODES 64
__global__ void k_pool2(const ushort* __restrict__ outbf, const int* __restrict__ batch,
                        float* __restrict__ pooled) {
    int f = threadIdx.x;   // 128
    int r0 = blockIdx.x * PNODES;
    if (r0 >= N_NODES) return;
    int end = r0 + PNODES; if (end > N_NODES) end = N_NODES;
    float m = 0.0f;        // relu floor
    int gcur = batch[r0];
    for (int i = r0; i < end; ++i) {
        int g = batch[i];
        if (g != gcur) {
            atomicMax((int*)&pooled[gcur * FDIM + f], __float_as_int(m));
            m = 0.0f; gcur = g;
        }
        uint u = outbf[(long)i * FDIM + f];
        m = fmaxf(m, __uint_as_float(u << 16));
    }
    atomicMax((int*)&pooled[gcur * FDIM + f], __float_as_int(m));
}

// ---------------- head GEMM + log_softmax ----------------
__global__ void k_head(const float* __restrict__ pooled, const float* __restrict__ W2,
                       const float* __restrict__ b2, float* __restrict__ out) {
    int g = blockIdx.x;
    int lane = threadIdx.x;
    int c = lane & 15;
    float acc = b2[c];
    for (int k = 0; k < FDIM; ++k) acc += pooled[g * FDIM + k] * W2[k * OUTF + c];
    float m = acc;
    for (int off = 1; off < 16; off <<= 1) m = fmaxf(m, __shfl_xor(m, off, 16));
    float s = expf(acc - m);
    for (int off = 1; off < 16; off <<= 1) s += __shfl_xor(s, off, 16);
    if (lane < 16) out[g * OUTF + c] = acc - m - logf(s);
}

extern "C" void kernel_launch(void* const* d_in, const int* in_sizes, int n_in,
                              void* d_out, int out_size, void* d_ws, size_t ws_size,
                              hipStream_t stream) {
    const float* x  = (const float*)d_in[0];
    const float* W1 = (const float*)d_in[1];
    const float* b1 = (const float*)d_in[2];
    const float* W2 = (const float*)d_in[3];
    const float* b2 = (const float*)d_in[4];
    const int* ei   = (const int*)d_in[5];
    const int* batch = (const int*)d_in[6];
    const int* src = ei;
    const int* dst = ei + N_EDGES;
    float* out = (float*)d_out;

    char* ws = (char*)d_ws;
    float*  dinv      = (float*) (ws + 0);          // 100000 f
    int*    row_start = (int*)   (ws + 400000);     // 100001 i
    float*  pooled    = (float*) (ws + 800064);     // 32768 f
    int*    bcount    = (int*)   (ws + 931200);     // BC_N i
    int*    boff      = (int*)   (ws + 1732032);    // BC_N+1 i
    int*    bsums     = (int*)   (ws + 2532864);    // 196 i
    int*    csr_src   = (int*)   (ws + 2533696);    // 1.6M i (6.4 MB)
    int2*   ebuf      = (int2*)  (ws + 8933696);    // 1.6M int2 (12.8 MB)
    ushort* hbf       = (ushort*)(ws + 21733696);   // N*128 bf16 (25.6 MB)
    ushort* outbf     = (ushort*)(ws + 47333696);   // N*128 bf16 (25.6 MB)
    ushort* wtbf      = (ushort*)(ws + 72933696);   // 128*128 bf16 (32 KB)
    // total ~73 MB

    k_zero   <<<128, 256, 0, stream>>>(pooled, row_start);
    k_bhist  <<<NBLK, 256, 0, stream>>>(dst, bcount);
    k_scan1g <<<BC_SCAN_NB, 256, 0, stream>>>(bcount, boff, bsums, BC_N);
    k_scan2g <<<1, 64, 0, stream>>>(bsums, boff, BC_SCAN_NB, BC_N, N_EDGES);
    k_scan3g <<<BC_SCAN_NB, 256, 0, stream>>>(boff, bsums, BC_N);
    k_bucket <<<NBLK, 256, 0, stream>>>(src, dst, boff, ebuf);
    k_build  <<<NB_BUCKET, 256, 0, stream>>>(ebuf, boff, row_start, dinv, csr_src);
    k_wcast  <<<64, 256, 0, stream>>>(W1, wtbf);
    k_gemm   <<<(N_NODES + BM - 1) / BM, 256, 0, stream>>>(x, wtbf, hbf);
    k_agg    <<<N_NODES / 8, 256, 0, stream>>>(hbf, dinv, row_start, csr_src, b1, outbf);
    k_pool2  <<<(N_NODES + PNODES - 1) / PNODES, FDIM, 0, stream>>>(outbf, batch, pooled);
    k_head   <<<NGRAPH, 64, 0, stream>>>(pooled, W2, b2, out);
}

// Round 14
// 276.112 us; speedup vs baseline: 10.7659x; 1.0728x over previous
//
#include <hip/hip_runtime.h>

#define N_NODES 100000
#define N_EDGES 1600000
#define FDIM 128
#define OUTF 16
#define NGRAPH 256

#define NBLK 256          // partition blocks
#define CHUNK 6250        // N_EDGES / NBLK (exact)
#define NB_BUCKET 391     // ceil(N_NODES/256), bucket = dst >> 8
#define BC_N (NB_BUCKET * NBLK)   // 100096
#define BC_SCAN_NB 98     // ceil(BC_N/1024)

typedef unsigned int uint;
typedef unsigned short ushort;
typedef short bf16x8 __attribute__((ext_vector_type(8)));
typedef float f32x4 __attribute__((ext_vector_type(4)));

__device__ inline uint pack_bf16(float a, float b) {
    uint ua = __float_as_uint(a); ua = (ua + 0x7fffu + ((ua >> 16) & 1u)) >> 16;
    uint ub = __float_as_uint(b); ub = (ub + 0x7fffu + ((ub >> 16) & 1u)) >> 16;
    return ua | (ub << 16);
}
__device__ inline ushort bf16_1(float a) {
    uint u = __float_as_uint(a);
    return (ushort)((u + 0x7fffu + ((u >> 16) & 1u)) >> 16);
}
__device__ inline void unpack_bf16(uint v, float& a, float& b) {
    a = __uint_as_float(v << 16);
    b = __uint_as_float(v & 0xffff0000u);
}

// ---------------- pass A: bucket histogram (+ fused pooled-zero, row_start seal, wcast) ----------------
__launch_bounds__(256)
__global__ void k_bhist(const int* __restrict__ dst, int* __restrict__ bcount,
                        float* __restrict__ pooled, int* __restrict__ row_start,
                        const float* __restrict__ W, ushort* __restrict__ wt) {
    __shared__ int hist[NB_BUCKET];
    int t = threadIdx.x, blk = blockIdx.x;
    int gi = blk * 256 + t;
    if (gi < NGRAPH * FDIM) pooled[gi] = 0.0f;           // zero pooled (blocks 0..127)
    if (gi < FDIM * FDIM) {                              // Wt[col][k] = bf16(W[k][col]) (blocks 0..63)
        int col = gi >> 7, k = gi & 127;
        wt[col * 128 + k] = bf16_1(W[k * 128 + col]);
    }
    if (gi == 0) row_start[N_NODES] = N_EDGES;
    for (int i = t; i < NB_BUCKET; i += 256) hist[i] = 0;
    __syncthreads();
    int base = blk * CHUNK;
    for (int j = t; j < CHUNK; j += 256) atomicAdd(&hist[dst[base + j] >> 8], 1);
    __syncthreads();
    for (int i = t; i < NB_BUCKET; i += 256) bcount[i * NBLK + blk] = hist[i];
}

// ---------------- generic exclusive scan (3 kernels) ----------------
__global__ void k_scan1g(const int* __restrict__ in, int* __restrict__ offs,
                         int* __restrict__ bsums, int n) {
    __shared__ int tmp[256];
    int t = threadIdx.x;
    int base = blockIdx.x * 1024 + t * 4;
    int c[4]; int s = 0;
#pragma unroll
    for (int j = 0; j < 4; ++j) { c[j] = (base + j < n) ? in[base + j] : 0; s += c[j]; }
    tmp[t] = s; __syncthreads();
    for (int off = 1; off < 256; off <<= 1) {
        int v = (t >= off) ? tmp[t - off] : 0;
        __syncthreads();
        tmp[t] += v;
        __syncthreads();
    }
    int run = tmp[t] - s;
#pragma unroll
    for (int j = 0; j < 4; ++j) { if (base + j < n) offs[base + j] = run; run += c[j]; }
    if (t == 255) bsums[blockIdx.x] = tmp[255];
}

__global__ void k_scan2g(int* __restrict__ bsums, int* __restrict__ offs,
                         int nb, int n, int total) {
    if (threadIdx.x == 0) {
        int acc = 0;
        for (int i = 0; i < nb; ++i) { int v = bsums[i]; bsums[i] = acc; acc += v; }
        offs[n] = total;
    }
}

__global__ void k_scan3g(int* __restrict__ offs, const int* __restrict__ bsums, int n) {
    int t = threadIdx.x;
    int base = blockIdx.x * 1024 + t * 4;
    int add = bsums[blockIdx.x];
#pragma unroll
    for (int j = 0; j < 4; ++j) if (base + j < n) offs[base + j] += add;
}

// ---------------- pass B: partition edges, packed key (d&255)<<17 | src ----------------
__launch_bounds__(256)
__global__ void k_bucket(const int* __restrict__ src, const int* __restrict__ dst,
                         const int* __restrict__ boff, uint* __restrict__ ebuf) {
    __shared__ int cur[NB_BUCKET];
    int t = threadIdx.x, blk = blockIdx.x;
    for (int i = t; i < NB_BUCKET; i += 256) cur[i] = boff[i * NBLK + blk];
    __syncthreads();
    int base = blk * CHUNK;
    for (int j = t; j < CHUNK; j += 256) {
        int d = dst[base + j], s = src[base + j];
        int pos = atomicAdd(&cur[d >> 8], 1);
        ebuf[pos] = ((uint)(d & 255) << 17) | (uint)s;
    }
}

// ---------------- pass C: per-bucket count + LDS scan -> row_start, dinv, csr ----------------
__launch_bounds__(256)
__global__ void k_build(const uint* __restrict__ ebuf, const int* __restrict__ boff,
                        int* __restrict__ row_start, float* __restrict__ dinv,
                        int* __restrict__ csr_src) {
    __shared__ int cnt[256], sh[256], cur[256];
    int t = threadIdx.x, b = blockIdx.x;
    int bstart = boff[b * NBLK];
    int bend   = boff[(b + 1) * NBLK];   // boff[BC_N] = N_EDGES for last bucket
    cnt[t] = 0;
    __syncthreads();
    for (int j = bstart + t; j < bend; j += 256)
        atomicAdd(&cnt[ebuf[j] >> 17], 1);
    __syncthreads();
    int c = cnt[t];
    sh[t] = c;
    __syncthreads();
    for (int o = 1; o < 256; o <<= 1) {
        int v = (t >= o) ? sh[t - o] : 0;
        __syncthreads();
        sh[t] += v;
        __syncthreads();
    }
    int rs = bstart + sh[t] - c;
    cur[t] = rs;
    int node = b * 256 + t;
    if (node < N_NODES) {
        row_start[node] = rs;
        dinv[node] = rsqrtf((float)c + 1.0f);
    }
    __syncthreads();
    for (int j = bstart + t; j < bend; j += 256) {
        uint e = ebuf[j];
        int pos = atomicAdd(&cur[e >> 17], 1);
        csr_src[pos] = (int)(e & 0x1FFFFu);
    }
}

// ---------------- h = x @ W1 via bf16 MFMA; epilogue pre-scales by dinv[row] ----------------
#define BM 128
#define LDP 136   // padded row (shorts): 272 B stride -> 2-way bank aliasing (free)
__launch_bounds__(256)
__global__ void k_gemm(const float* __restrict__ x, const ushort* __restrict__ wt,
                       const float* __restrict__ dinv, ushort* __restrict__ hbf) {
    __shared__ ushort AL[BM][LDP];
    __shared__ ushort WL[128][LDP];
    int t = threadIdx.x;
    int r0 = blockIdx.x * BM;

    for (int i = t; i < 128 * 16; i += 256) {
        int r = i >> 4, s = i & 15;
        *(uint4*)&WL[r][s * 8] = *(const uint4*)&wt[r * 128 + s * 8];
    }
    {
        int r = t >> 1, half = t & 1;
        int grow = r0 + r; if (grow >= N_NODES) grow = N_NODES - 1;
        const float4* xp = (const float4*)(x + (long)grow * FDIM + half * 64);
        ushort* ap = &AL[r][half * 64];
#pragma unroll
        for (int i = 0; i < 16; ++i) {
            float4 v = xp[i];
            uint2 p;
            p.x = pack_bf16(v.x, v.y);
            p.y = pack_bf16(v.z, v.w);
            *(uint2*)&ap[i * 4] = p;
        }
    }
    __syncthreads();

    int w = t >> 6, l = t & 63;
    int lr = l & 15;
    int lk = (l >> 4) * 8;
    f32x4 acc[2][8] = {};
#pragma unroll
    for (int kc = 0; kc < 4; ++kc) {
        int ko = kc * 32 + lk;
        bf16x8 a0 = *(const bf16x8*)&AL[w * 32 + lr][ko];
        bf16x8 a1 = *(const bf16x8*)&AL[w * 32 + 16 + lr][ko];
        bf16x8 b[8];
#pragma unroll
        for (int ct = 0; ct < 8; ++ct) b[ct] = *(const bf16x8*)&WL[ct * 16 + lr][ko];
#pragma unroll
        for (int ct = 0; ct < 8; ++ct) {
            acc[0][ct] = __builtin_amdgcn_mfma_f32_16x16x32_bf16(a0, b[ct], acc[0][ct], 0, 0, 0);
            acc[1][ct] = __builtin_amdgcn_mfma_f32_16x16x32_bf16(a1, b[ct], acc[1][ct], 0, 0, 0);
        }
    }
    // C/D: col=lane&15, row=(lane>>4)*4+reg [m89]; store dinv[row]*acc as bf16
    int rbase = r0 + w * 32 + (l >> 4) * 4;
#pragma unroll
    for (int rt = 0; rt < 2; ++rt) {
#pragma unroll
        for (int reg = 0; reg < 4; ++reg) {
            int row = rbase + rt * 16 + reg;
            if (row < N_NODES) {
                float dv = dinv[row];
#pragma unroll
                for (int ct = 0; ct < 8; ++ct)
                    hbf[(long)row * FDIM + ct * 16 + lr] = bf16_1(dv * acc[rt][ct][reg]);
            }
        }
    }
}

// ---------------- CSR gather-aggregate over pre-scaled rows ----------------
__launch_bounds__(256)
__global__ void k_agg(const ushort* __restrict__ hbf, const float* __restrict__ dinv,
                      const int* __restrict__ row_start, const int* __restrict__ csr_src,
                      const float* __restrict__ b1, ushort* __restrict__ outbf) {
    int t = threadIdx.x;
    int lane = t & 31;
    int node = blockIdx.x * 8 + (t >> 5);
    const uint2* hb = (const uint2*)hbf;
    uint2 v = hb[node * 32 + lane];      // self term: dinv_d * h_d (pre-scaled)
    float s0, s1, s2, s3;
    unpack_bf16(v.x, s0, s1); unpack_bf16(v.y, s2, s3);
    int beg = row_start[node], end = row_start[node + 1];
    int j = beg;
    for (; j + 3 < end; j += 4) {
        uint2 va = hb[csr_src[j] * 32 + lane];
        uint2 vb = hb[csr_src[j + 1] * 32 + lane];
        uint2 vc = hb[csr_src[j + 2] * 32 + lane];
        uint2 vd = hb[csr_src[j + 3] * 32 + lane];
        float a0, a1, a2, a3;
        unpack_bf16(va.x, a0, a1); unpack_bf16(va.y, a2, a3);
        s0 += a0; s1 += a1; s2 += a2; s3 += a3;
        unpack_bf16(vb.x, a0, a1); unpack_bf16(vb.y, a2, a3);
        s0 += a0; s1 += a1; s2 += a2; s3 += a3;
        unpack_bf16(vc.x, a0, a1); unpack_bf16(vc.y, a2, a3);
        s0 += a0; s1 += a1; s2 += a2; s3 += a3;
        unpack_bf16(vd.x, a0, a1); unpack_bf16(vd.y, a2, a3);
        s0 += a0; s1 += a1; s2 += a2; s3 += a3;
    }
    for (; j < end; ++j) {
        uint2 va = hb[csr_src[j] * 32 + lane];
        float a0, a1, a2, a3;
        unpack_bf16(va.x, a0, a1); unpack_bf16(va.y, a2, a3);
        s0 += a0; s1 += a1; s2 += a2; s3 += a3;
    }
    float dd = dinv[node];
    float4 bv = ((const float4*)b1)[lane];
    uint2 o;
    o.x = pack_bf16(dd * s0 + bv.x, dd * s1 + bv.y);
    o.y = pack_bf16(dd * s2 + bv.z, dd * s3 + bv.w);
    ((uint2*)outbf)[node * 32 + lane] = o;
}

// ---------------- pool: run-length max + int atomicMax (vals >= 0, relu folded) ----------------
#define PNODES 64
__global__ void k_pool2(const ushort* __restrict__ outbf, const int* __restrict__ batch,
                        float* __restrict__ pooled) {
    int f = threadIdx.x;
    int r0 = blockIdx.x * PNODES;
    if (r0 >= N_NODES) return;
    int end = r0 + PNODES; if (end > N_NODES) end = N_NODES;
    float m = 0.0f;
    int gcur = batch[r0];
    for (int i = r0; i < end; ++i) {
        int g = batch[i];
        if (g != gcur) {
            atomicMax((int*)&pooled[gcur * FDIM + f], __float_as_int(m));
            m = 0.0f; gcur = g;
        }
        uint u = outbf[(long)i * FDIM + f];
        m = fmaxf(m, __uint_as_float(u << 16));
    }
    atomicMax((int*)&pooled[gcur * FDIM + f], __float_as_int(m));
}

// ---------------- head GEMM + log_softmax ----------------
__global__ void k_head(const float* __restrict__ pooled, const float* __restrict__ W2,
                       const float* __restrict__ b2, float* __restrict__ out) {
    int g = blockIdx.x;
    int lane = threadIdx.x;
    int c = lane & 15;
    float acc = b2[c];
    for (int k = 0; k < FDIM; ++k) acc += pooled[g * FDIM + k] * W2[k * OUTF + c];
    float m = acc;
    for (int off = 1; off < 16; off <<= 1) m = fmaxf(m, __shfl_xor(m, off, 16));
    float s = expf(acc - m);
    for (int off = 1; off < 16; off <<= 1) s += __shfl_xor(s, off, 16);
    if (lane < 16) out[g * OUTF + c] = acc - m - logf(s);
}

extern "C" void kernel_launch(void* const* d_in, const int* in_sizes, int n_in,
                              void* d_out, int out_size, void* d_ws, size_t ws_size,
                              hipStream_t stream) {
    const float* x  = (const float*)d_in[0];
    const float* W1 = (const float*)d_in[1];
    const float* b1 = (const float*)d_in[2];
    const float* W2 = (const float*)d_in[3];
    const float* b2 = (const float*)d_in[4];
    const int* ei   = (const int*)d_in[5];
    const int* batch = (const int*)d_in[6];
    const int* src = ei;
    const int* dst = ei + N_EDGES;
    float* out = (float*)d_out;

    char* ws = (char*)d_ws;
    float*  dinv      = (float*) (ws + 0);          // 100000 f
    int*    row_start = (int*)   (ws + 400000);     // 100001 i
    float*  pooled    = (float*) (ws + 800064);     // 32768 f
    int*    bcount    = (int*)   (ws + 931200);     // BC_N i (400384 B)
    int*    boff      = (int*)   (ws + 1331648);    // BC_N+1 i (400388 B)
    int*    bsums     = (int*)   (ws + 1732096);    // 98 i
    int*    csr_src   = (int*)   (ws + 1732544);    // 1.6M i (6.4 MB)
    uint*   ebuf      = (uint*)  (ws + 8132544);    // 1.6M uint (6.4 MB)
    ushort* hbf       = (ushort*)(ws + 14532544);   // N*128 bf16 (25.6 MB)
    ushort* outbf     = (ushort*)(ws + 40132544);   // N*128 bf16 (25.6 MB)
    ushort* wtbf      = (ushort*)(ws + 65732544);   // 128*128 bf16 (32 KB)
    // total ~65.8 MB

    k_bhist  <<<NBLK, 256, 0, stream>>>(dst, bcount, pooled, row_start, W1, wtbf);
    k_scan1g <<<BC_SCAN_NB, 256, 0, stream>>>(bcount, boff, bsums, BC_N);
    k_scan2g <<<1, 64, 0, stream>>>(bsums, boff, BC_SCAN_NB, BC_N, N_EDGES);
    k_scan3g <<<BC_SCAN_NB, 256, 0, stream>>>(boff, bsums, BC_N);
    k_bucket <<<NBLK, 256, 0, stream>>>(src, dst, boff, ebuf);
    k_build  <<<NB_BUCKET, 256, 0, stream>>>(ebuf, boff, row_start, dinv, csr_src);
    k_gemm   <<<(N_NODES + BM - 1) / BM, 256, 0, stream>>>(x, wtbf, dinv, hbf);
    k_agg    <<<N_NODES / 8, 256, 0, stream>>>(hbf, dinv, row_start, csr_src, b1, outbf);
    k_pool2  <<<(N_NODES + PNODES - 1) / PNODES, FDIM, 0, stream>>>(outbf, batch, pooled);
    k_head   <<<NGRAPH, 64, 0, stream>>>(pooled, W2, b2, out);
}

// Round 17
// 252.818 us; speedup vs baseline: 11.7578x; 1.0921x over previous
//
#include <hip/hip_runtime.h>

#define N_NODES 100000
#define N_EDGES 1600000
#define FDIM 128
#define OUTF 16
#define NGRAPH 256

#define NBLK 256          // partition blocks
#define CHUNK 6250        // N_EDGES / NBLK (exact)
#define NB_BUCKET 391     // ceil(N_NODES/256), bucket = dst >> 8
#define BC_N (NB_BUCKET * NBLK)   // 100096
#define BC_SCAN_NB 98     // ceil(BC_N/1024)

typedef unsigned int uint;
typedef unsigned short ushort;
typedef short bf16x8 __attribute__((ext_vector_type(8)));
typedef float f32x4 __attribute__((ext_vector_type(4)));

__device__ inline uint pack_bf16(float a, float b) {
    uint ua = __float_as_uint(a); ua = (ua + 0x7fffu + ((ua >> 16) & 1u)) >> 16;
    uint ub = __float_as_uint(b); ub = (ub + 0x7fffu + ((ub >> 16) & 1u)) >> 16;
    return ua | (ub << 16);
}
__device__ inline ushort bf16_1(float a) {
    uint u = __float_as_uint(a);
    return (ushort)((u + 0x7fffu + ((u >> 16) & 1u)) >> 16);
}
__device__ inline void unpack_bf16(uint v, float& a, float& b) {
    a = __uint_as_float(v << 16);
    b = __uint_as_float(v & 0xffff0000u);
}

// ---------------- pass A: bucket histogram (+ fused pooled-zero, row_start seal, wcast) ----------------
__launch_bounds__(256)
__global__ void k_bhist(const int* __restrict__ dst, int* __restrict__ bcount,
                        float* __restrict__ pooled, int* __restrict__ row_start,
                        const float* __restrict__ W, ushort* __restrict__ wt) {
    __shared__ int hist[NB_BUCKET];
    int t = threadIdx.x, blk = blockIdx.x;
    int gi = blk * 256 + t;
    if (gi < NGRAPH * FDIM) pooled[gi] = 0.0f;
    if (gi < FDIM * FDIM) {
        int col = gi >> 7, k = gi & 127;
        wt[col * 128 + k] = bf16_1(W[k * 128 + col]);
    }
    if (gi == 0) row_start[N_NODES] = N_EDGES;
    for (int i = t; i < NB_BUCKET; i += 256) hist[i] = 0;
    __syncthreads();
    int base = blk * CHUNK;
    for (int j = t; j < CHUNK; j += 256) atomicAdd(&hist[dst[base + j] >> 8], 1);
    __syncthreads();
    for (int i = t; i < NB_BUCKET; i += 256) bcount[i * NBLK + blk] = hist[i];
}

// ---------------- generic exclusive scan (3 kernels) ----------------
__global__ void k_scan1g(const int* __restrict__ in, int* __restrict__ offs,
                         int* __restrict__ bsums, int n) {
    __shared__ int tmp[256];
    int t = threadIdx.x;
    int base = blockIdx.x * 1024 + t * 4;
    int c[4]; int s = 0;
#pragma unroll
    for (int j = 0; j < 4; ++j) { c[j] = (base + j < n) ? in[base + j] : 0; s += c[j]; }
    tmp[t] = s; __syncthreads();
    for (int off = 1; off < 256; off <<= 1) {
        int v = (t >= off) ? tmp[t - off] : 0;
        __syncthreads();
        tmp[t] += v;
        __syncthreads();
    }
    int run = tmp[t] - s;
#pragma unroll
    for (int j = 0; j < 4; ++j) { if (base + j < n) offs[base + j] = run; run += c[j]; }
    if (t == 255) bsums[blockIdx.x] = tmp[255];
}

__global__ void k_scan2g(int* __restrict__ bsums, int* __restrict__ offs,
                         int nb, int n, int total) {
    if (threadIdx.x == 0) {
        int acc = 0;
        for (int i = 0; i < nb; ++i) { int v = bsums[i]; bsums[i] = acc; acc += v; }
        offs[n] = total;
    }
}

__global__ void k_scan3g(int* __restrict__ offs, const int* __restrict__ bsums, int n) {
    int t = threadIdx.x;
    int base = blockIdx.x * 1024 + t * 4;
    int add = bsums[blockIdx.x];
#pragma unroll
    for (int j = 0; j < 4; ++j) if (base + j < n) offs[base + j] += add;
}

// ---------------- pass B: partition edges, packed key (d&255)<<17 | src ----------------
__launch_bounds__(256)
__global__ void k_bucket(const int* __restrict__ src, const int* __restrict__ dst,
                         const int* __restrict__ boff, uint* __restrict__ ebuf) {
    __shared__ int cur[NB_BUCKET];
    int t = threadIdx.x, blk = blockIdx.x;
    for (int i = t; i < NB_BUCKET; i += 256) cur[i] = boff[i * NBLK + blk];
    __syncthreads();
    int base = blk * CHUNK;
    for (int j = t; j < CHUNK; j += 256) {
        int d = dst[base + j], s = src[base + j];
        int pos = atomicAdd(&cur[d >> 8], 1);
        ebuf[pos] = ((uint)(d & 255) << 17) | (uint)s;
    }
}

// ---------------- pass C: per-bucket count + LDS scan -> row_start, dinv, csr ----------------
__launch_bounds__(256)
__global__ void k_build(const uint* __restrict__ ebuf, const int* __restrict__ boff,
                        int* __restrict__ row_start, float* __restrict__ dinv,
                        int* __restrict__ csr_src) {
    __shared__ int cnt[256], sh[256], cur[256];
    int t = threadIdx.x, b = blockIdx.x;
    int bstart = boff[b * NBLK];
    int bend   = boff[(b + 1) * NBLK];
    cnt[t] = 0;
    __syncthreads();
    for (int j = bstart + t; j < bend; j += 256)
        atomicAdd(&cnt[ebuf[j] >> 17], 1);
    __syncthreads();
    int c = cnt[t];
    sh[t] = c;
    __syncthreads();
    for (int o = 1; o < 256; o <<= 1) {
        int v = (t >= o) ? sh[t - o] : 0;
        __syncthreads();
        sh[t] += v;
        __syncthreads();
    }
    int rs = bstart + sh[t] - c;
    cur[t] = rs;
    int node = b * 256 + t;
    if (node < N_NODES) {
        row_start[node] = rs;
        dinv[node] = rsqrtf((float)c + 1.0f);
    }
    __syncthreads();
    for (int j = bstart + t; j < bend; j += 256) {
        uint e = ebuf[j];
        int pos = atomicAdd(&cur[e >> 17], 1);
        csr_src[pos] = (int)(e & 0x1FFFFu);
    }
}

// ---------------- h = x @ W1 via bf16 MFMA; epilogue pre-scales by dinv[row] ----------------
#define BM 128
#define LDP 136
__launch_bounds__(256)
__global__ void k_gemm(const float* __restrict__ x, const ushort* __restrict__ wt,
                       const float* __restrict__ dinv, ushort* __restrict__ hbf) {
    __shared__ ushort AL[BM][LDP];
    __shared__ ushort WL[128][LDP];
    int t = threadIdx.x;
    int r0 = blockIdx.x * BM;

    for (int i = t; i < 128 * 16; i += 256) {
        int r = i >> 4, s = i & 15;
        *(uint4*)&WL[r][s * 8] = *(const uint4*)&wt[r * 128 + s * 8];
    }
    {
        int r = t >> 1, half = t & 1;
        int grow = r0 + r; if (grow >= N_NODES) grow = N_NODES - 1;
        const float4* xp = (const float4*)(x + (long)grow * FDIM + half * 64);
        ushort* ap = &AL[r][half * 64];
#pragma unroll
        for (int i = 0; i < 16; ++i) {
            float4 v = xp[i];
            uint2 p;
            p.x = pack_bf16(v.x, v.y);
            p.y = pack_bf16(v.z, v.w);
            *(uint2*)&ap[i * 4] = p;
        }
    }
    __syncthreads();

    int w = t >> 6, l = t & 63;
    int lr = l & 15;
    int lk = (l >> 4) * 8;
    f32x4 acc[2][8] = {};
#pragma unroll
    for (int kc = 0; kc < 4; ++kc) {
        int ko = kc * 32 + lk;
        bf16x8 a0 = *(const bf16x8*)&AL[w * 32 + lr][ko];
        bf16x8 a1 = *(const bf16x8*)&AL[w * 32 + 16 + lr][ko];
        bf16x8 b[8];
#pragma unroll
        for (int ct = 0; ct < 8; ++ct) b[ct] = *(const bf16x8*)&WL[ct * 16 + lr][ko];
#pragma unroll
        for (int ct = 0; ct < 8; ++ct) {
            acc[0][ct] = __builtin_amdgcn_mfma_f32_16x16x32_bf16(a0, b[ct], acc[0][ct], 0, 0, 0);
            acc[1][ct] = __builtin_amdgcn_mfma_f32_16x16x32_bf16(a1, b[ct], acc[1][ct], 0, 0, 0);
        }
    }
    int rbase = r0 + w * 32 + (l >> 4) * 4;
#pragma unroll
    for (int rt = 0; rt < 2; ++rt) {
#pragma unroll
        for (int reg = 0; reg < 4; ++reg) {
            int row = rbase + rt * 16 + reg;
            if (row < N_NODES) {
                float dv = dinv[row];
#pragma unroll
                for (int ct = 0; ct < 8; ++ct)
                    hbf[(long)row * FDIM + ct * 16 + lr] = bf16_1(dv * acc[rt][ct][reg]);
            }
        }
    }
}

// ---------------- CSR gather-aggregate + fused relu/max-pool ----------------
// 16 lanes x uint4 (16B) per row -> 4 rows/wave, 16 nodes/block; pool via LDS stage
#define AGN 16   // nodes per block
__launch_bounds__(256)
__global__ void k_agg(const ushort* __restrict__ hbf, const float* __restrict__ dinv,
                      const int* __restrict__ row_start, const int* __restrict__ csr_src,
                      const float* __restrict__ b1, const int* __restrict__ batch,
                      float* __restrict__ pooled) {
    __shared__ float P[AGN][FDIM];   // 8 KB relu'd rows
    __shared__ int sb[AGN];
    int t = threadIdx.x;
    int lane = t & 15;               // 8 feats per lane (uint4 = 8 bf16)
    int ni = t >> 4;                 // node-in-block 0..15
    int r0 = blockIdx.x * AGN;
    int node = r0 + ni;              // grid exact: 6250*16 = 100000
    if (t < AGN) sb[t] = batch[r0 + t];

    const uint4* hb = (const uint4*)hbf;   // 16 uint4 per row
    uint4 v = hb[node * 16 + lane];        // self term (pre-scaled by dinv)
    float s0, s1, s2, s3, s4, s5, s6, s7;
    unpack_bf16(v.x, s0, s1); unpack_bf16(v.y, s2, s3);
    unpack_bf16(v.z, s4, s5); unpack_bf16(v.w, s6, s7);
    int beg = row_start[node], end = row_start[node + 1];
    int j = beg;
    for (; j + 3 < end; j += 4) {
        uint4 va = hb[csr_src[j] * 16 + lane];
        uint4 vb = hb[csr_src[j + 1] * 16 + lane];
        uint4 vc = hb[csr_src[j + 2] * 16 + lane];
        uint4 vd = hb[csr_src[j + 3] * 16 + lane];
        float a0, a1;
        unpack_bf16(va.x, a0, a1); s0 += a0; s1 += a1;
        unpack_bf16(va.y, a0, a1); s2 += a0; s3 += a1;
        unpack_bf16(va.z, a0, a1); s4 += a0; s5 += a1;
        unpack_bf16(va.w, a0, a1); s6 += a0; s7 += a1;
        unpack_bf16(vb.x, a0, a1); s0 += a0; s1 += a1;
        unpack_bf16(vb.y, a0, a1); s2 += a0; s3 += a1;
        unpack_bf16(vb.z, a0, a1); s4 += a0; s5 += a1;
        unpack_bf16(vb.w, a0, a1); s6 += a0; s7 += a1;
        unpack_bf16(vc.x, a0, a1); s0 += a0; s1 += a1;
        unpack_bf16(vc.y, a0, a1); s2 += a0; s3 += a1;
        unpack_bf16(vc.z, a0, a1); s4 += a0; s5 += a1;
        unpack_bf16(vc.w, a0, a1); s6 += a0; s7 += a1;
        unpack_bf16(vd.x, a0, a1); s0 += a0; s1 += a1;
        unpack_bf16(vd.y, a0, a1); s2 += a0; s3 += a1;
        unpack_bf16(vd.z, a0, a1); s4 += a0; s5 += a1;
        unpack_bf16(vd.w, a0, a1); s6 += a0; s7 += a1;
    }
    for (; j < end; ++j) {
        uint4 va = hb[csr_src[j] * 16 + lane];
        float a0, a1;
        unpack_bf16(va.x, a0, a1); s0 += a0; s1 += a1;
        unpack_bf16(va.y, a0, a1); s2 += a0; s3 += a1;
        unpack_bf16(va.z, a0, a1); s4 += a0; s5 += a1;
        unpack_bf16(va.w, a0, a1); s6 += a0; s7 += a1;
    }
    float dd = dinv[node];
    const float4* b4 = (const float4*)b1;
    float4 bva = b4[lane * 2], bvb = b4[lane * 2 + 1];
    float* pr = &P[ni][lane * 8];
    pr[0] = fmaxf(0.0f, dd * s0 + bva.x);
    pr[1] = fmaxf(0.0f, dd * s1 + bva.y);
    pr[2] = fmaxf(0.0f, dd * s2 + bva.z);
    pr[3] = fmaxf(0.0f, dd * s3 + bva.w);
    pr[4] = fmaxf(0.0f, dd * s4 + bvb.x);
    pr[5] = fmaxf(0.0f, dd * s5 + bvb.y);
    pr[6] = fmaxf(0.0f, dd * s6 + bvb.z);
    pr[7] = fmaxf(0.0f, dd * s7 + bvb.w);
    __syncthreads();
    // run-length max over 16 sorted-batch nodes, one atomicMax per feature per run
    if (t < FDIM) {
        float m = 0.0f;
        int gcur = sb[0];
#pragma unroll
        for (int i = 0; i < AGN; ++i) {
            int g = sb[i];
            if (g != gcur) {
                atomicMax((int*)&pooled[gcur * FDIM + t], __float_as_int(m));
                m = 0.0f; gcur = g;
            }
            m = fmaxf(m, P[i][t]);
        }
        atomicMax((int*)&pooled[gcur * FDIM + t], __float_as_int(m));
    }
}

// ---------------- head GEMM + log_softmax ----------------
__global__ void k_head(const float* __restrict__ pooled, const float* __restrict__ W2,
                       const float* __restrict__ b2, float* __restrict__ out) {
    int g = blockIdx.x;
    int lane = threadIdx.x;
    int c = lane & 15;
    float acc = b2[c];
    for (int k = 0; k < FDIM; ++k) acc += pooled[g * FDIM + k] * W2[k * OUTF + c];
    float m = acc;
    for (int off = 1; off < 16; off <<= 1) m = fmaxf(m, __shfl_xor(m, off, 16));
    float s = expf(acc - m);
    for (int off = 1; off < 16; off <<= 1) s += __shfl_xor(s, off, 16);
    if (lane < 16) out[g * OUTF + c] = acc - m - logf(s);
}

extern "C" void kernel_launch(void* const* d_in, const int* in_sizes, int n_in,
                              void* d_out, int out_size, void* d_ws, size_t ws_size,
                              hipStream_t stream) {
    const float* x  = (const float*)d_in[0];
    const float* W1 = (const float*)d_in[1];
    const float* b1 = (const float*)d_in[2];
    const float* W2 = (const float*)d_in[3];
    const float* b2 = (const float*)d_in[4];
    const int* ei   = (const int*)d_in[5];
    const int* batch = (const int*)d_in[6];
    const int* src = ei;
    const int* dst = ei + N_EDGES;
    float* out = (float*)d_out;

    char* ws = (char*)d_ws;
    float*  dinv      = (float*) (ws + 0);          // 100000 f
    int*    row_start = (int*)   (ws + 400000);     // 100001 i
    float*  pooled    = (float*) (ws + 800064);     // 32768 f
    int*    bcount    = (int*)   (ws + 931200);     // BC_N i
    int*    boff      = (int*)   (ws + 1331648);    // BC_N+1 i
    int*    bsums     = (int*)   (ws + 1732096);    // 98 i
    int*    csr_src   = (int*)   (ws + 1732544);    // 1.6M i (6.4 MB)
    uint*   ebuf      = (uint*)  (ws + 8132544);    // 1.6M uint (6.4 MB)
    ushort* hbf       = (ushort*)(ws + 14532544);   // N*128 bf16 (25.6 MB)
    ushort* wtbf      = (ushort*)(ws + 40132544);   // 128*128 bf16 (32 KB)
    // total ~40.2 MB

    k_bhist  <<<NBLK, 256, 0, stream>>>(dst, bcount, pooled, row_start, W1, wtbf);
    k_scan1g <<<BC_SCAN_NB, 256, 0, stream>>>(bcount, boff, bsums, BC_N);
    k_scan2g <<<1, 64, 0, stream>>>(bsums, boff, BC_SCAN_NB, BC_N, N_EDGES);
    k_scan3g <<<BC_SCAN_NB, 256, 0, stream>>>(boff, bsums, BC_N);
    k_bucket <<<NBLK, 256, 0, stream>>>(src, dst, boff, ebuf);
    k_build  <<<NB_BUCKET, 256, 0, stream>>>(ebuf, boff, row_start, dinv, csr_src);
    k_gemm   <<<(N_NODES + BM - 1) / BM, 256, 0, stream>>>(x, wtbf, dinv, hbf);
    k_agg    <<<N_NODES / AGN, 256, 0, stream>>>(hbf, dinv, row_start, csr_src, b1, batch, pooled);
    k_head   <<<NGRAPH, 64, 0, stream>>>(pooled, W2, b2, out);
}